// Round 4
// baseline (1548.648 us; speedup 1.0000x reference)
//
#include <hip/hip_runtime.h>
#include <hip/hip_bf16.h>

typedef __attribute__((ext_vector_type(4))) float f32x4;
typedef __attribute__((ext_vector_type(8))) short bf16x8;
typedef __attribute__((ext_vector_type(4))) short bf16x4;

#define MFMA16(a,b,c) __builtin_amdgcn_mfma_f32_16x16x32_bf16(a,b,c,0,0,0)
// async global->LDS DMA, 16B/lane; LDS dest = uniform base + lane*16
#define GLLDS16(g, l) __builtin_amdgcn_global_load_lds( \
    (const __attribute__((address_space(1))) unsigned int*)(g), \
    (__attribute__((address_space(3))) unsigned int*)(l), 16, 0, 0)

constexpr int BATCH = 2, SEQ = 2048, EMB = 4096;
constexpr int NHQ = 32, NHKV = 8, HD = 128, GRP = 4;

static __device__ __forceinline__ short f2bf(float f) {
    union { float f; unsigned u; } v; v.f = f;
    unsigned r = v.u + 0x7fff + ((v.u >> 16) & 1);   // RNE; inputs finite
    return (short)(r >> 16);
}
static __device__ __forceinline__ bf16x8 cvt8(f32x4 a, f32x4 b) {
    bf16x8 r;
    r[0]=f2bf(a[0]); r[1]=f2bf(a[1]); r[2]=f2bf(a[2]); r[3]=f2bf(a[3]);
    r[4]=f2bf(b[0]); r[5]=f2bf(b[1]); r[6]=f2bf(b[2]); r[7]=f2bf(b[3]);
    return r;
}

// f32 -> bf16 bulk convert (memory-bound)
__global__ __launch_bounds__(256) void cvt_bf16(
    const float* __restrict__ src, short* __restrict__ dst, int n8)
{
    int i = blockIdx.x * blockDim.x + threadIdx.x;
    const int stride = gridDim.x * blockDim.x;
    for (; i < n8; i += stride) {
        f32x4 a = *(const f32x4*)(src + (size_t)i * 8);
        f32x4 b = *(const f32x4*)(src + (size_t)i * 8 + 4);
        *(bf16x8*)(dst + (size_t)i * 8) = cvt8(a, b);
    }
}

// ---- shared GEMM pieces (128x128 tile, 4 waves, K-step 64) ----

struct GemmCtx {
    int lane, wave, ln, quad, wm, wn, rowbase, colbase;
};

static __device__ __forceinline__ void gemm_mainloop(
    short (&As)[128][64], short (&Bs)[128][64],
    const short* __restrict__ A, const short* __restrict__ W,
    int K, const GemmCtx& c, f32x4 (&acc)[4][4])
{
    for (int kk = 0; kk < K; kk += 64) {
        __syncthreads();   // barrier drains prior ds_reads before overwrite
        // bf16 tile 128x64: 8 chunks/row, 8 rows per wave-load, 4 loads/wave
#pragma unroll
        for (int i = 0; i < 4; ++i) {
            const int row = c.wave * 32 + i * 8;
            const short* g = A + (size_t)(c.rowbase + row + (c.lane >> 3)) * K + kk + (c.lane & 7) * 8;
            GLLDS16(g, &As[row][0]);
        }
#pragma unroll
        for (int i = 0; i < 4; ++i) {
            const int row = c.wave * 32 + i * 8;
            const short* g = W + (size_t)(c.colbase + row + (c.lane >> 3)) * K + kk + (c.lane & 7) * 8;
            GLLDS16(g, &Bs[row][0]);
        }
        __syncthreads();   // drains vmcnt (global_load_lds) per m97 semantics

#pragma unroll
        for (int kc = 0; kc < 2; ++kc) {
            bf16x8 af[4], bfr[4];
#pragma unroll
            for (int i = 0; i < 4; i++)
                af[i] = *(const bf16x8*)&As[c.wm * 64 + i * 16 + c.ln][kc * 32 + c.quad * 8];
#pragma unroll
            for (int i = 0; i < 4; i++)
                bfr[i] = *(const bf16x8*)&Bs[c.wn * 64 + i * 16 + c.ln][kc * 32 + c.quad * 8];
#pragma unroll
            for (int i = 0; i < 4; i++)
#pragma unroll
                for (int j = 0; j < 4; j++)
                    acc[i][j] = MFMA16(af[i], bfr[j], acc[i][j]);
        }
    }
}

// epilogue. C/D layout: col = ln, row = quad*4 + reg  [measured m89/m91]
template<int MODE>
static __device__ __forceinline__ void gemm_epilogue(
    const f32x4 (&acc)[4][4], const float* __restrict__ bias,
    const float* __restrict__ freqs, void* __restrict__ outv,
    int N, int NH, const GemmCtx& c)
{
#pragma unroll
    for (int i = 0; i < 4; i++) {
        const int r0 = c.rowbase + c.wm * 64 + i * 16 + c.quad * 4;
#pragma unroll
        for (int j = 0; j < 4; j++) {
            const int col = c.colbase + c.wn * 64 + j * 16 + c.ln;
            const float bv = bias[col];
            if (MODE == 0) {
                float* out = (float*)outv;
#pragma unroll
                for (int rg = 0; rg < 4; rg++)
                    out[(size_t)(r0 + rg) * N + col] = acc[i][j][rg] + bv;
            } else if (MODE == 1) {
                short* out = (short*)outv;
                const int h = col / HD, d = col % HD;
#pragma unroll
                for (int rg = 0; rg < 4; rg++) {
                    const int r = r0 + rg;
                    const int bb = r / SEQ, t = r % SEQ;
                    const float v = acc[i][j][rg] + bv;
                    const float p = __shfl_xor(v, 1);     // pair column lives in lane^1
                    const int fi = (t * (HD / 2) + (d >> 1)) * 2;
                    const float co = freqs[fi], si = freqs[fi + 1];
                    const float y = (d & 1) ? (v * co + p * si) : (v * co - p * si);
                    out[(((size_t)bb * NH + h) * SEQ + t) * HD + d] = f2bf(y);
                }
            } else { // MODE 2: Vt[b][h][d][t], 4 consecutive t -> one 8B store
                short* out = (short*)outv;
                const int h = col / HD, d = col % HD;
                const int bb = r0 / SEQ, t0 = r0 % SEQ;
                bf16x4 pk;
#pragma unroll
                for (int rg = 0; rg < 4; rg++) pk[rg] = f2bf(acc[i][j][rg] + bv);
                *(bf16x4*)(out + (((size_t)bb * NHKV + h) * HD + d) * SEQ + t0) = pk;
            }
        }
    }
}

// C[M][N] = A[M][K] * W[N][K]^T + bias (single projection)
template<int MODE>
__global__ __launch_bounds__(256) void gemm_bt(
    const short* __restrict__ A, const short* __restrict__ W,
    const float* __restrict__ bias, const float* __restrict__ freqs,
    void* __restrict__ outv, int M, int N, int K, int NH)
{
    __shared__ short As[128][64];
    __shared__ short Bs[128][64];
    const int tid = threadIdx.x;
    GemmCtx c;
    c.lane = tid & 63; c.wave = tid >> 6;
    c.ln = c.lane & 15; c.quad = c.lane >> 4;
    c.wm = c.wave >> 1; c.wn = c.wave & 1;
    c.rowbase = blockIdx.y * 128; c.colbase = blockIdx.x * 128;

    f32x4 acc[4][4];
#pragma unroll
    for (int i = 0; i < 4; i++)
#pragma unroll
        for (int j = 0; j < 4; j++) acc[i][j] = (f32x4){0.f, 0.f, 0.f, 0.f};

    gemm_mainloop(As, Bs, A, W, K, c, acc);
    gemm_epilogue<MODE>(acc, bias, freqs, outv, N, NH, c);
}

// Fused K-proj (z=0, RoPE->Kr) and V-proj (z=1, ->Vt): doubles resident blocks
// for the narrow N=1024 projections (256 wg alone = 1 block/CU, latency-bound).
__global__ __launch_bounds__(256) void gemm_kv(
    const short* __restrict__ Ak, const short* __restrict__ Wkb,
    const float* __restrict__ bk, const float* __restrict__ freqs,
    void* __restrict__ outK,
    const short* __restrict__ Av, const short* __restrict__ Wvb,
    const float* __restrict__ bv, void* __restrict__ outV,
    int M, int N, int K)
{
    __shared__ short As[128][64];
    __shared__ short Bs[128][64];
    const int tid = threadIdx.x;
    GemmCtx c;
    c.lane = tid & 63; c.wave = tid >> 6;
    c.ln = c.lane & 15; c.quad = c.lane >> 4;
    c.wm = c.wave >> 1; c.wn = c.wave & 1;
    c.rowbase = blockIdx.y * 128; c.colbase = blockIdx.x * 128;
    const int z = blockIdx.z;

    const short* A = (z == 0) ? Ak : Av;
    const short* W = (z == 0) ? Wkb : Wvb;

    f32x4 acc[4][4];
#pragma unroll
    for (int i = 0; i < 4; i++)
#pragma unroll
        for (int j = 0; j < 4; j++) acc[i][j] = (f32x4){0.f, 0.f, 0.f, 0.f};

    gemm_mainloop(As, Bs, A, W, K, c, acc);
    if (z == 0) gemm_epilogue<1>(acc, bk, freqs, outK, N, NHKV, c);
    else        gemm_epilogue<2>(acc, bv, nullptr, outV, N, NHKV, c);
}

// Flash attention, causal. Block = 4 waves = 4 Q-heads of one KV group, 32 q-rows each.
// K/V LDS: 16B-chunk XOR-swizzled by row [T2, rule 21]. SINGLE buffer + serial
// stage (r1 structure: pipelining regressed twice — cross-block overlap already
// hides staging). __launch_bounds__(256,3): VGPR<=170 so 43KB LDS => 3 blocks/CU.
__global__ __launch_bounds__(256, 3) void attn(
    const short* __restrict__ Qr, const short* __restrict__ Kr,
    const short* __restrict__ Vt, short* __restrict__ Y)
{
    __shared__ short Ks[64][128];      // [key][d]   chunk ^= key&7
    __shared__ short Vs[128][64];      // [d][key]   chunk ^= d&7
    __shared__ short Ps[4][16][80];    // per-wave P round-trip (pad 80: <=4-way)

    const int tid = threadIdx.x;
    const int lane = tid & 63, wave = tid >> 6;
    const int ln = lane & 15, quad = lane >> 4;
    const int qt = (int)gridDim.x - 1 - (int)blockIdx.x;  // heavy (diagonal) blocks first
    const int kvh = blockIdx.y, b = blockIdx.z;
    const int h = kvh * GRP + wave;
    const int qbase = qt * 32;
    const int sx = (ln & 7) << 3;      // read-side XOR, in shorts

    const short* Qh = Qr + (((size_t)b * NHQ + h) * SEQ + qbase) * HD;
    const short* Kh = Kr + ((size_t)b * NHKV + kvh) * SEQ * HD;
    const short* Vh = Vt + ((size_t)b * NHKV + kvh) * (size_t)HD * SEQ;

    bf16x8 aQ[2][4];   // A-layout: A[m=ln][k=quad*8+j], dc = 32-wide K chunk
#pragma unroll
    for (int mi = 0; mi < 2; mi++)
#pragma unroll
        for (int dc = 0; dc < 4; dc++)
            aQ[mi][dc] = *(const bf16x8*)(Qh + (size_t)(mi * 16 + ln) * HD + dc * 32 + quad * 8);

    f32x4 oa[2][8];
#pragma unroll
    for (int mi = 0; mi < 2; mi++)
#pragma unroll
        for (int dt = 0; dt < 8; dt++) oa[mi][dt] = (f32x4){0.f, 0.f, 0.f, 0.f};
    float mrun[2][4], lrun[2][4];
#pragma unroll
    for (int mi = 0; mi < 2; mi++)
#pragma unroll
        for (int rg = 0; rg < 4; rg++) { mrun[mi][rg] = -INFINITY; lrun[mi][rg] = 0.f; }

    auto stage = [&](int kt) {
        // K tile 64x128: source chunk pre-swizzled so LDS[r][c] = global chunk c^(r&7)
#pragma unroll
        for (int i = 0; i < 4; ++i) {
            const int row0 = wave * 16 + i * 4;
            const int rr = row0 + (lane >> 4);
            const short* g = Kh + (size_t)(kt * 64 + rr) * HD + (((lane & 15) ^ (rr & 7)) << 3);
            GLLDS16(g, &Ks[row0][0]);
        }
        // V^T tile 128x64
#pragma unroll
        for (int i = 0; i < 4; ++i) {
            const int row0 = wave * 32 + i * 8;
            const int rr = row0 + (lane >> 3);
            const short* g = Vh + (size_t)rr * SEQ + kt * 64 + (((lane & 7) ^ (lane >> 3)) << 3);
            GLLDS16(g, &Vs[row0][0]);
        }
    };

    auto compute = [&](int kt) {
#pragma unroll
        for (int mi = 0; mi < 2; mi++) {
            float s[4][4];
            __builtin_amdgcn_s_setprio(1);
#pragma unroll
            for (int nt = 0; nt < 4; nt++) {
                f32x4 sa = (f32x4){0.f, 0.f, 0.f, 0.f};
#pragma unroll
                for (int dc = 0; dc < 4; dc++) {
                    bf16x8 bK = *(const bf16x8*)&Ks[nt * 16 + ln][(dc * 32 + quad * 8) ^ sx];
                    sa = MFMA16(aQ[mi][dc], bK, sa);
                }
                const int kg = kt * 64 + nt * 16 + ln;   // key idx (C col = ln)
#pragma unroll
                for (int rg = 0; rg < 4; rg++) {
                    const int qg = qbase + mi * 16 + quad * 4 + rg;
                    s[nt][rg] = (kg <= qg) ? sa[rg] * 0.08838834764831845f : -INFINITY;
                }
            }
            __builtin_amdgcn_s_setprio(0);

            // row max (16 lanes share a row: 4-step xor reduce)
            float mx4[4];
#pragma unroll
            for (int rg = 0; rg < 4; rg++) {
                float mx = fmaxf(fmaxf(s[0][rg], s[1][rg]), fmaxf(s[2][rg], s[3][rg]));
                mx = fmaxf(mx, __shfl_xor(mx, 1));
                mx = fmaxf(mx, __shfl_xor(mx, 2));
                mx = fmaxf(mx, __shfl_xor(mx, 4));
                mx = fmaxf(mx, __shfl_xor(mx, 8));
                mx4[rg] = mx;
            }
            // T13 defer-max: skip rescale while growth <= 8 (P bounded by e^8)
            bool ok = (mx4[0] <= mrun[mi][0] + 8.f) & (mx4[1] <= mrun[mi][1] + 8.f) &
                      (mx4[2] <= mrun[mi][2] + 8.f) & (mx4[3] <= mrun[mi][3] + 8.f);
            if (!__all(ok)) {
#pragma unroll
                for (int rg = 0; rg < 4; rg++) {
                    const float mnew = fmaxf(mrun[mi][rg], mx4[rg]);
                    const float a = __expf(mrun[mi][rg] - mnew);
                    mrun[mi][rg] = mnew;
                    lrun[mi][rg] *= a;
                    mx4[rg] = a;   // reuse as rescale factor
                }
#pragma unroll
                for (int dt = 0; dt < 8; dt++)
#pragma unroll
                    for (int rg = 0; rg < 4; rg++) oa[mi][dt][rg] *= mx4[rg];
            }
#pragma unroll
            for (int rg = 0; rg < 4; rg++) {
                float rs = 0.f;
#pragma unroll
                for (int nt = 0; nt < 4; nt++) {
                    const float p = __expf(s[nt][rg] - mrun[mi][rg]);
                    s[nt][rg] = p; rs += p;
                }
                rs += __shfl_xor(rs, 1); rs += __shfl_xor(rs, 2);
                rs += __shfl_xor(rs, 4); rs += __shfl_xor(rs, 8);
                lrun[mi][rg] += rs;
            }
            // P: C-layout (row=quad*4+rg, col=nt*16+ln) -> LDS -> A-layout reads.
            // Wave-private buffer: intra-wave LDS is ordered, no block barrier.
#pragma unroll
            for (int nt = 0; nt < 4; nt++)
#pragma unroll
                for (int rg = 0; rg < 4; rg++)
                    Ps[wave][quad * 4 + rg][nt * 16 + ln] = f2bf(s[nt][rg]);
            __builtin_amdgcn_s_setprio(1);
#pragma unroll
            for (int kc = 0; kc < 2; kc++) {
                bf16x8 aP = *(const bf16x8*)&Ps[wave][ln][kc * 32 + quad * 8];
#pragma unroll
                for (int dt = 0; dt < 8; dt++) {
                    bf16x8 bV = *(const bf16x8*)&Vs[dt * 16 + ln][(kc * 32 + quad * 8) ^ sx];
                    oa[mi][dt] = MFMA16(aP, bV, oa[mi][dt]);
                }
            }
            __builtin_amdgcn_s_setprio(0);
        }
    };

    const int nkt = (qbase + 95) >> 6;   // ceil((qbase+32)/64): stop at the diagonal
    for (int kt = 0; kt < nkt; ++kt) {
        __syncthreads();                 // prior tile's ds_reads done before overwrite
        stage(kt);
        __syncthreads();                 // vmcnt(0): tile resident
        compute(kt);
    }

    // epilogue: Y[b][t][h*HD + d]
#pragma unroll
    for (int mi = 0; mi < 2; mi++) {
#pragma unroll
        for (int rg = 0; rg < 4; rg++) {
            const float inv = 1.f / lrun[mi][rg];
            const int t = qbase + mi * 16 + quad * 4 + rg;
            const size_t rowoff = ((size_t)b * SEQ + t) * EMB + h * HD;
#pragma unroll
            for (int dt = 0; dt < 8; dt++)
                Y[rowoff + dt * 16 + ln] = f2bf(oa[mi][dt][rg] * inv);
        }
    }
}

extern "C" void kernel_launch(void* const* d_in, const int* in_sizes, int n_in,
                              void* d_out, int out_size, void* d_ws, size_t ws_size,
                              hipStream_t stream) {
    const float* q  = (const float*)d_in[0];
    const float* k  = (const float*)d_in[1];
    const float* v  = (const float*)d_in[2];
    const float* fr = (const float*)d_in[3];
    // d_in[4] = mask (int32): causal tril, hardcoded in attn
    const float* Wq = (const float*)d_in[5];
    const float* bq = (const float*)d_in[6];
    const float* Wk = (const float*)d_in[7];
    const float* bk = (const float*)d_in[8];
    const float* Wv = (const float*)d_in[9];
    const float* bv = (const float*)d_in[10];
    const float* Wo = (const float*)d_in[11];
    const float* bo = (const float*)d_in[12];

    char* ws = (char*)d_ws;
    short* Qr = (short*)(ws);                    // [B][HQ][T][D]   32 MiB bf16; also v-act scratch pre-Qproj
    short* Kr = (short*)(ws + 33554432);         // [B][HKV][T][D]   8 MiB
    short* Vt = (short*)(ws + 41943040);         // [B][HKV][D][T]   8 MiB
    short* Yb = (short*)(ws + 50331648);         // 32 MiB: bf16 activations / Y (post-attn)
    short* Wb = (short*)(ws + 83886080);         // bf16 weight buf 32 MiB (reused; Wk@0 + Wv@8MiB)
    float* out = (float*)d_out;                  // reference output dtype = float32

    const int M = BATCH * SEQ;
    dim3 blk(256);
    const int big8 = EMB * EMB / 8, small8 = NHKV * HD * EMB / 8, act8 = M * EMB / 8;
    short* WbK = Wb;
    short* WbV = Wb + (size_t)NHKV * HD * EMB;   // +8 MiB (in shorts)

    // K & V projections fused (both act buffers live: k-acts in Yb, v-acts in Qr slot)
    cvt_bf16<<<1024, blk, 0, stream>>>(Wk, WbK, small8);
    cvt_bf16<<<1024, blk, 0, stream>>>(Wv, WbV, small8);
    cvt_bf16<<<1024, blk, 0, stream>>>(k, Yb, act8);
    cvt_bf16<<<1024, blk, 0, stream>>>(v, Qr, act8);
    gemm_kv<<<dim3((NHKV * HD) / 128, M / 128, 2), blk, 0, stream>>>(
        Yb, WbK, bk, fr, Kr, Qr, WbV, bv, Vt, M, NHKV * HD, EMB);
    // Q projection (overwrites Qr after v-acts consumed; stream-ordered)
    cvt_bf16<<<1024, blk, 0, stream>>>(Wq, Wb, big8);
    cvt_bf16<<<1024, blk, 0, stream>>>(q, Yb, act8);
    gemm_bt<1><<<dim3(EMB / 128, M / 128), blk, 0, stream>>>(Yb, Wb, bq, fr, Qr, M, EMB, EMB, NHQ);
    // attention
    attn<<<dim3(SEQ / 32, NHKV, BATCH), blk, 0, stream>>>(Qr, Kr, Vt, Yb);
    // output projection
    cvt_bf16<<<1024, blk, 0, stream>>>(Wo, Wb, big8);
    gemm_bt<0><<<dim3(EMB / 128, M / 128), blk, 0, stream>>>(Yb, Wb, bo, nullptr, out, M, EMB, EMB, 0);
}

// Round 5
// 1227.111 us; speedup vs baseline: 1.2620x; 1.2620x over previous
//
#include <hip/hip_runtime.h>
#include <hip/hip_bf16.h>

typedef __attribute__((ext_vector_type(4))) float f32x4;
typedef __attribute__((ext_vector_type(8))) short bf16x8;
typedef __attribute__((ext_vector_type(4))) short bf16x4;

#define MFMA16(a,b,c) __builtin_amdgcn_mfma_f32_16x16x32_bf16(a,b,c,0,0,0)
// async global->LDS DMA, 16B/lane; LDS dest = uniform base + lane*16
#define GLLDS16(g, l) __builtin_amdgcn_global_load_lds( \
    (const __attribute__((address_space(1))) unsigned int*)(g), \
    (__attribute__((address_space(3))) unsigned int*)(l), 16, 0, 0)

constexpr int BATCH = 2, SEQ = 2048, EMB = 4096;
constexpr int NHQ = 32, NHKV = 8, HD = 128, GRP = 4;

static __device__ __forceinline__ short f2bf(float f) {
    union { float f; unsigned u; } v; v.f = f;
    unsigned r = v.u + 0x7fff + ((v.u >> 16) & 1);   // RNE; inputs finite
    return (short)(r >> 16);
}
static __device__ __forceinline__ bf16x8 cvt8(f32x4 a, f32x4 b) {
    bf16x8 r;
    r[0]=f2bf(a[0]); r[1]=f2bf(a[1]); r[2]=f2bf(a[2]); r[3]=f2bf(a[3]);
    r[4]=f2bf(b[0]); r[5]=f2bf(b[1]); r[6]=f2bf(b[2]); r[7]=f2bf(b[3]);
    return r;
}

// f32 -> bf16 bulk convert (memory-bound)
__global__ __launch_bounds__(256) void cvt_bf16(
    const float* __restrict__ src, short* __restrict__ dst, int n8)
{
    int i = blockIdx.x * blockDim.x + threadIdx.x;
    const int stride = gridDim.x * blockDim.x;
    for (; i < n8; i += stride) {
        f32x4 a = *(const f32x4*)(src + (size_t)i * 8);
        f32x4 b = *(const f32x4*)(src + (size_t)i * 8 + 4);
        *(bf16x8*)(dst + (size_t)i * 8) = cvt8(a, b);
    }
}

// ---- shared GEMM pieces (128x128 tile, 4 waves, K-step 64) ----

struct GemmCtx {
    int lane, wave, ln, quad, wm, wn, rowbase, colbase;
};

static __device__ __forceinline__ void gemm_mainloop(
    short (&As)[128][64], short (&Bs)[128][64],
    const short* __restrict__ A, const short* __restrict__ W,
    int K, const GemmCtx& c, f32x4 (&acc)[4][4])
{
    for (int kk = 0; kk < K; kk += 64) {
        __syncthreads();   // barrier drains prior ds_reads before overwrite
        // bf16 tile 128x64: 8 chunks/row, 8 rows per wave-load, 4 loads/wave
#pragma unroll
        for (int i = 0; i < 4; ++i) {
            const int row = c.wave * 32 + i * 8;
            const short* g = A + (size_t)(c.rowbase + row + (c.lane >> 3)) * K + kk + (c.lane & 7) * 8;
            GLLDS16(g, &As[row][0]);
        }
#pragma unroll
        for (int i = 0; i < 4; ++i) {
            const int row = c.wave * 32 + i * 8;
            const short* g = W + (size_t)(c.colbase + row + (c.lane >> 3)) * K + kk + (c.lane & 7) * 8;
            GLLDS16(g, &Bs[row][0]);
        }
        __syncthreads();   // drains vmcnt (global_load_lds) per m97 semantics

#pragma unroll
        for (int kc = 0; kc < 2; ++kc) {
            bf16x8 af[4], bfr[4];
#pragma unroll
            for (int i = 0; i < 4; i++)
                af[i] = *(const bf16x8*)&As[c.wm * 64 + i * 16 + c.ln][kc * 32 + c.quad * 8];
#pragma unroll
            for (int i = 0; i < 4; i++)
                bfr[i] = *(const bf16x8*)&Bs[c.wn * 64 + i * 16 + c.ln][kc * 32 + c.quad * 8];
#pragma unroll
            for (int i = 0; i < 4; i++)
#pragma unroll
                for (int j = 0; j < 4; j++)
                    acc[i][j] = MFMA16(af[i], bfr[j], acc[i][j]);
        }
    }
}

// epilogue. C/D layout: col = ln, row = quad*4 + reg  [measured m89/m91]
template<int MODE>
static __device__ __forceinline__ void gemm_epilogue(
    const f32x4 (&acc)[4][4], const float* __restrict__ bias,
    const float* __restrict__ freqs, void* __restrict__ outv,
    int N, int NH, const GemmCtx& c)
{
#pragma unroll
    for (int i = 0; i < 4; i++) {
        const int r0 = c.rowbase + c.wm * 64 + i * 16 + c.quad * 4;
#pragma unroll
        for (int j = 0; j < 4; j++) {
            const int col = c.colbase + c.wn * 64 + j * 16 + c.ln;
            const float bv = bias[col];
            if (MODE == 0) {
                float* out = (float*)outv;
#pragma unroll
                for (int rg = 0; rg < 4; rg++)
                    out[(size_t)(r0 + rg) * N + col] = acc[i][j][rg] + bv;
            } else if (MODE == 1) {
                short* out = (short*)outv;
                const int h = col / HD, d = col % HD;
#pragma unroll
                for (int rg = 0; rg < 4; rg++) {
                    const int r = r0 + rg;
                    const int bb = r / SEQ, t = r % SEQ;
                    const float v = acc[i][j][rg] + bv;
                    const float p = __shfl_xor(v, 1);     // pair column lives in lane^1
                    const int fi = (t * (HD / 2) + (d >> 1)) * 2;
                    const float co = freqs[fi], si = freqs[fi + 1];
                    const float y = (d & 1) ? (v * co + p * si) : (v * co - p * si);
                    out[(((size_t)bb * NH + h) * SEQ + t) * HD + d] = f2bf(y);
                }
            } else { // MODE 2: Vt[b][h][d][t], 4 consecutive t -> one 8B store
                short* out = (short*)outv;
                const int h = col / HD, d = col % HD;
                const int bb = r0 / SEQ, t0 = r0 % SEQ;
                bf16x4 pk;
#pragma unroll
                for (int rg = 0; rg < 4; rg++) pk[rg] = f2bf(acc[i][j][rg] + bv);
                *(bf16x4*)(out + (((size_t)bb * NHKV + h) * HD + d) * SEQ + t0) = pk;
            }
        }
    }
}

// C[M][N] = A[M][K] * W[N][K]^T + bias (single projection)
template<int MODE>
__global__ __launch_bounds__(256) void gemm_bt(
    const short* __restrict__ A, const short* __restrict__ W,
    const float* __restrict__ bias, const float* __restrict__ freqs,
    void* __restrict__ outv, int M, int N, int K, int NH)
{
    __shared__ short As[128][64];
    __shared__ short Bs[128][64];
    const int tid = threadIdx.x;
    GemmCtx c;
    c.lane = tid & 63; c.wave = tid >> 6;
    c.ln = c.lane & 15; c.quad = c.lane >> 4;
    c.wm = c.wave >> 1; c.wn = c.wave & 1;
    c.rowbase = blockIdx.y * 128; c.colbase = blockIdx.x * 128;

    f32x4 acc[4][4];
#pragma unroll
    for (int i = 0; i < 4; i++)
#pragma unroll
        for (int j = 0; j < 4; j++) acc[i][j] = (f32x4){0.f, 0.f, 0.f, 0.f};

    gemm_mainloop(As, Bs, A, W, K, c, acc);
    gemm_epilogue<MODE>(acc, bias, freqs, outv, N, NH, c);
}

// Fused K-proj (z=0, RoPE->Kr) and V-proj (z=1, ->Vt): doubles resident blocks
// for the narrow N=1024 projections (256 wg alone = 1 block/CU, latency-bound).
__global__ __launch_bounds__(256) void gemm_kv(
    const short* __restrict__ Ak, const short* __restrict__ Wkb,
    const float* __restrict__ bk, const float* __restrict__ freqs,
    void* __restrict__ outK,
    const short* __restrict__ Av, const short* __restrict__ Wvb,
    const float* __restrict__ bv, void* __restrict__ outV,
    int M, int N, int K)
{
    __shared__ short As[128][64];
    __shared__ short Bs[128][64];
    const int tid = threadIdx.x;
    GemmCtx c;
    c.lane = tid & 63; c.wave = tid >> 6;
    c.ln = c.lane & 15; c.quad = c.lane >> 4;
    c.wm = c.wave >> 1; c.wn = c.wave & 1;
    c.rowbase = blockIdx.y * 128; c.colbase = blockIdx.x * 128;
    const int z = blockIdx.z;

    const short* A = (z == 0) ? Ak : Av;
    const short* W = (z == 0) ? Wkb : Wvb;

    f32x4 acc[4][4];
#pragma unroll
    for (int i = 0; i < 4; i++)
#pragma unroll
        for (int j = 0; j < 4; j++) acc[i][j] = (f32x4){0.f, 0.f, 0.f, 0.f};

    gemm_mainloop(As, Bs, A, W, K, c, acc);
    if (z == 0) gemm_epilogue<1>(acc, bk, freqs, outK, N, NHKV, c);
    else        gemm_epilogue<2>(acc, bv, nullptr, outV, N, NHKV, c);
}

// Flash attention, causal. Block = 4 waves = 4 Q-heads of one KV group, 32 q-rows each.
// K/V LDS: 16B-chunk XOR-swizzled by row [T2, rule 21]. SINGLE buffer + serial
// stage (pipelining regressed twice; cross-block overlap hides staging).
// PLAIN __launch_bounds__(256): r4's (256,3) min-waves hint made the compiler
// chase 6 waves/EU -> 84 VGPR -> accumulator spills -> 2.3 GB scratch traffic.
// Natural allocation (~144-160 VGPR) can reach 3 waves/SIMD without spilling.
__global__ __launch_bounds__(256) void attn(
    const short* __restrict__ Qr, const short* __restrict__ Kr,
    const short* __restrict__ Vt, short* __restrict__ Y)
{
    __shared__ short Ks[64][128];      // [key][d]   chunk ^= key&7
    __shared__ short Vs[128][64];      // [d][key]   chunk ^= d&7
    __shared__ short Ps[4][16][80];    // per-wave P round-trip (pad 80: <=4-way)

    const int tid = threadIdx.x;
    const int lane = tid & 63, wave = tid >> 6;
    const int ln = lane & 15, quad = lane >> 4;
    const int qt = (int)gridDim.x - 1 - (int)blockIdx.x;  // heavy (diagonal) blocks first
    const int kvh = blockIdx.y, b = blockIdx.z;
    const int h = kvh * GRP + wave;
    const int qbase = qt * 32;
    const int sx = (ln & 7) << 3;      // read-side XOR, in shorts

    const short* Qh = Qr + (((size_t)b * NHQ + h) * SEQ + qbase) * HD;
    const short* Kh = Kr + ((size_t)b * NHKV + kvh) * SEQ * HD;
    const short* Vh = Vt + ((size_t)b * NHKV + kvh) * (size_t)HD * SEQ;

    bf16x8 aQ[2][4];   // A-layout: A[m=ln][k=quad*8+j], dc = 32-wide K chunk
#pragma unroll
    for (int mi = 0; mi < 2; mi++)
#pragma unroll
        for (int dc = 0; dc < 4; dc++)
            aQ[mi][dc] = *(const bf16x8*)(Qh + (size_t)(mi * 16 + ln) * HD + dc * 32 + quad * 8);

    f32x4 oa[2][8];
#pragma unroll
    for (int mi = 0; mi < 2; mi++)
#pragma unroll
        for (int dt = 0; dt < 8; dt++) oa[mi][dt] = (f32x4){0.f, 0.f, 0.f, 0.f};
    float mrun[2][4], lrun[2][4];
#pragma unroll
    for (int mi = 0; mi < 2; mi++)
#pragma unroll
        for (int rg = 0; rg < 4; rg++) { mrun[mi][rg] = -INFINITY; lrun[mi][rg] = 0.f; }

    auto stage = [&](int kt) {
        // K tile 64x128: source chunk pre-swizzled so LDS[r][c] = global chunk c^(r&7)
#pragma unroll
        for (int i = 0; i < 4; ++i) {
            const int row0 = wave * 16 + i * 4;
            const int rr = row0 + (lane >> 4);
            const short* g = Kh + (size_t)(kt * 64 + rr) * HD + (((lane & 15) ^ (rr & 7)) << 3);
            GLLDS16(g, &Ks[row0][0]);
        }
        // V^T tile 128x64
#pragma unroll
        for (int i = 0; i < 4; ++i) {
            const int row0 = wave * 32 + i * 8;
            const int rr = row0 + (lane >> 3);
            const short* g = Vh + (size_t)rr * SEQ + kt * 64 + (((lane & 7) ^ (lane >> 3)) << 3);
            GLLDS16(g, &Vs[row0][0]);
        }
    };

    auto compute = [&](int kt) {
#pragma unroll
        for (int mi = 0; mi < 2; mi++) {
            float s[4][4];
            __builtin_amdgcn_s_setprio(1);
#pragma unroll
            for (int nt = 0; nt < 4; nt++) {
                f32x4 sa = (f32x4){0.f, 0.f, 0.f, 0.f};
#pragma unroll
                for (int dc = 0; dc < 4; dc++) {
                    bf16x8 bK = *(const bf16x8*)&Ks[nt * 16 + ln][(dc * 32 + quad * 8) ^ sx];
                    sa = MFMA16(aQ[mi][dc], bK, sa);
                }
                const int kg = kt * 64 + nt * 16 + ln;   // key idx (C col = ln)
#pragma unroll
                for (int rg = 0; rg < 4; rg++) {
                    const int qg = qbase + mi * 16 + quad * 4 + rg;
                    s[nt][rg] = (kg <= qg) ? sa[rg] * 0.08838834764831845f : -INFINITY;
                }
            }
            __builtin_amdgcn_s_setprio(0);

            // row max (16 lanes share a row: 4-step xor reduce)
            float mx4[4];
#pragma unroll
            for (int rg = 0; rg < 4; rg++) {
                float mx = fmaxf(fmaxf(s[0][rg], s[1][rg]), fmaxf(s[2][rg], s[3][rg]));
                mx = fmaxf(mx, __shfl_xor(mx, 1));
                mx = fmaxf(mx, __shfl_xor(mx, 2));
                mx = fmaxf(mx, __shfl_xor(mx, 4));
                mx = fmaxf(mx, __shfl_xor(mx, 8));
                mx4[rg] = mx;
            }
            // T13 defer-max: skip rescale while growth <= 8 (P bounded by e^8)
            bool ok = (mx4[0] <= mrun[mi][0] + 8.f) & (mx4[1] <= mrun[mi][1] + 8.f) &
                      (mx4[2] <= mrun[mi][2] + 8.f) & (mx4[3] <= mrun[mi][3] + 8.f);
            if (!__all(ok)) {
#pragma unroll
                for (int rg = 0; rg < 4; rg++) {
                    const float mnew = fmaxf(mrun[mi][rg], mx4[rg]);
                    const float a = __expf(mrun[mi][rg] - mnew);
                    mrun[mi][rg] = mnew;
                    lrun[mi][rg] *= a;
                    mx4[rg] = a;   // reuse as rescale factor
                }
#pragma unroll
                for (int dt = 0; dt < 8; dt++)
#pragma unroll
                    for (int rg = 0; rg < 4; rg++) oa[mi][dt][rg] *= mx4[rg];
            }
#pragma unroll
            for (int rg = 0; rg < 4; rg++) {
                float rs = 0.f;
#pragma unroll
                for (int nt = 0; nt < 4; nt++) {
                    const float p = __expf(s[nt][rg] - mrun[mi][rg]);
                    s[nt][rg] = p; rs += p;
                }
                rs += __shfl_xor(rs, 1); rs += __shfl_xor(rs, 2);
                rs += __shfl_xor(rs, 4); rs += __shfl_xor(rs, 8);
                lrun[mi][rg] += rs;
            }
            // P: C-layout (row=quad*4+rg, col=nt*16+ln) -> LDS -> A-layout reads.
            // Wave-private buffer: intra-wave LDS is ordered, no block barrier.
#pragma unroll
            for (int nt = 0; nt < 4; nt++)
#pragma unroll
                for (int rg = 0; rg < 4; rg++)
                    Ps[wave][quad * 4 + rg][nt * 16 + ln] = f2bf(s[nt][rg]);
            __builtin_amdgcn_s_setprio(1);
#pragma unroll
            for (int kc = 0; kc < 2; kc++) {
                bf16x8 aP = *(const bf16x8*)&Ps[wave][ln][kc * 32 + quad * 8];
#pragma unroll
                for (int dt = 0; dt < 8; dt++) {
                    bf16x8 bV = *(const bf16x8*)&Vs[dt * 16 + ln][(kc * 32 + quad * 8) ^ sx];
                    oa[mi][dt] = MFMA16(aP, bV, oa[mi][dt]);
                }
            }
            __builtin_amdgcn_s_setprio(0);
        }
    };

    const int nkt = (qbase + 95) >> 6;   // ceil((qbase+32)/64): stop at the diagonal
    for (int kt = 0; kt < nkt; ++kt) {
        __syncthreads();                 // prior tile's ds_reads done before overwrite
        stage(kt);
        __syncthreads();                 // vmcnt(0): tile resident
        compute(kt);
    }

    // epilogue: Y[b][t][h*HD + d]
#pragma unroll
    for (int mi = 0; mi < 2; mi++) {
#pragma unroll
        for (int rg = 0; rg < 4; rg++) {
            const float inv = 1.f / lrun[mi][rg];
            const int t = qbase + mi * 16 + quad * 4 + rg;
            const size_t rowoff = ((size_t)b * SEQ + t) * EMB + h * HD;
#pragma unroll
            for (int dt = 0; dt < 8; dt++)
                Y[rowoff + dt * 16 + ln] = f2bf(oa[mi][dt][rg] * inv);
        }
    }
}

extern "C" void kernel_launch(void* const* d_in, const int* in_sizes, int n_in,
                              void* d_out, int out_size, void* d_ws, size_t ws_size,
                              hipStream_t stream) {
    const float* q  = (const float*)d_in[0];
    const float* k  = (const float*)d_in[1];
    const float* v  = (const float*)d_in[2];
    const float* fr = (const float*)d_in[3];
    // d_in[4] = mask (int32): causal tril, hardcoded in attn
    const float* Wq = (const float*)d_in[5];
    const float* bq = (const float*)d_in[6];
    const float* Wk = (const float*)d_in[7];
    const float* bk = (const float*)d_in[8];
    const float* Wv = (const float*)d_in[9];
    const float* bv = (const float*)d_in[10];
    const float* Wo = (const float*)d_in[11];
    const float* bo = (const float*)d_in[12];

    char* ws = (char*)d_ws;
    short* Qr = (short*)(ws);                    // [B][HQ][T][D]   32 MiB bf16; also v-act scratch pre-Qproj
    short* Kr = (short*)(ws + 33554432);         // [B][HKV][T][D]   8 MiB
    short* Vt = (short*)(ws + 41943040);         // [B][HKV][D][T]   8 MiB
    short* Yb = (short*)(ws + 50331648);         // 32 MiB: bf16 activations / Y (post-attn)
    short* Wb = (short*)(ws + 83886080);         // bf16 weight buf 32 MiB (reused; Wk@0 + Wv@8MiB)
    float* out = (float*)d_out;                  // reference output dtype = float32

    const int M = BATCH * SEQ;
    dim3 blk(256);
    const int big8 = EMB * EMB / 8, small8 = NHKV * HD * EMB / 8, act8 = M * EMB / 8;
    short* WbK = Wb;
    short* WbV = Wb + (size_t)NHKV * HD * EMB;   // +8 MiB (in shorts)

    // K & V projections fused (both act buffers live: k-acts in Yb, v-acts in Qr slot)
    cvt_bf16<<<1024, blk, 0, stream>>>(Wk, WbK, small8);
    cvt_bf16<<<1024, blk, 0, stream>>>(Wv, WbV, small8);
    cvt_bf16<<<1024, blk, 0, stream>>>(k, Yb, act8);
    cvt_bf16<<<1024, blk, 0, stream>>>(v, Qr, act8);
    gemm_kv<<<dim3((NHKV * HD) / 128, M / 128, 2), blk, 0, stream>>>(
        Yb, WbK, bk, fr, Kr, Qr, WbV, bv, Vt, M, NHKV * HD, EMB);
    // Q projection (overwrites Qr after v-acts consumed; stream-ordered)
    cvt_bf16<<<1024, blk, 0, stream>>>(Wq, Wb, big8);
    cvt_bf16<<<1024, blk, 0, stream>>>(q, Yb, act8);
    gemm_bt<1><<<dim3(EMB / 128, M / 128), blk, 0, stream>>>(Yb, Wb, bq, fr, Qr, M, EMB, EMB, NHQ);
    // attention
    attn<<<dim3(SEQ / 32, NHKV, BATCH), blk, 0, stream>>>(Qr, Kr, Vt, Yb);
    // output projection
    cvt_bf16<<<1024, blk, 0, stream>>>(Wo, Wb, big8);
    gemm_bt<0><<<dim3(EMB / 128, M / 128), blk, 0, stream>>>(Yb, Wb, bo, nullptr, out, M, EMB, EMB, 0);
}